// Round 13
// baseline (842.687 us; speedup 1.0000x reference)
//
#include <hip/hip_runtime.h>

// FourierBlock: per (b, c): rfft(4096) -> keep top-16 |X| bins -> irfft.
//
// Round 16: bracket the register demand. Measured: (512,2) cap128 ->
// allocator picks 116, ZERO spill, occ 23%, 675 us; (512,4) cap64 ->
// heavy spill (FETCH 546/WRITE 702 MB), occ 45%, 614 us. True demand in
// (64,116]. This round: __launch_bounds__(512,3) -> 6 waves/SIMD -> cap 85
// (waves/SIMD = 512/VGPR per m69 steps), 3 blocks x 8 waves = 24 waves/CU
// (75%), LDS 35KB allows 4 so VGPR binds. 85 is a 21-reg squeeze from the
// preferred 116 (reschedule), not round-12's 52-reg amputation (spill).
// The known demand PEAK -- 8 unrolled float4 loads keeping ~32 VGPRs of
// landing zone live -- is halved by chunking the load loop (unroll 1 outer,
// 4 loads/chunk). Everything else identical to the round-11/12 structure
// whose no-spill traffic signature is FETCH 65.7 MB / WRITE == 131072 KB.

#define SWZ(i) ((i) ^ (((i) >> 4) & 15))

__device__ __forceinline__ int drev8(int x) {
  // reverse the four octal digits of a 12-bit index (involution)
  return ((x & 7) << 9) | ((x & 0x38) << 3) | ((x >> 3) & 0x38) | ((x >> 9) & 7);
}

__device__ __forceinline__ float2 cmulf(float2 a, float c, float s) {
  return make_float2(a.x * c - a.y * s, a.x * s + a.y * c);
}

__device__ __forceinline__ float2 cadd(float2 a, float2 b) { return make_float2(a.x + b.x, a.y + b.y); }
__device__ __forceinline__ float2 csub(float2 a, float2 b) { return make_float2(a.x - b.x, a.y - b.y); }
__device__ __forceinline__ float2 cmulnegi(float2 a) { return make_float2(a.y, -a.x); }      // a * (-i)
__device__ __forceinline__ float2 cmulposi(float2 a) { return make_float2(-a.y, a.x); }      // a * (+i)

// 8-point DFT in registers, natural-order input AND output.
__device__ __forceinline__ void dft8(float2* a) {
  const float R = 0.7071067811865476f;
  float2 t0 = cadd(a[0], a[4]), t1 = cadd(a[1], a[5]);
  float2 t2 = cadd(a[2], a[6]), t3 = cadd(a[3], a[7]);
  float2 u0 = csub(a[0], a[4]);
  float2 d1 = csub(a[1], a[5]);
  float2 u1 = make_float2(R * (d1.x + d1.y), R * (d1.y - d1.x));   // * W8^1
  float2 u2 = cmulnegi(csub(a[2], a[6]));                          // * W8^2
  float2 d3 = csub(a[3], a[7]);
  float2 u3 = make_float2(R * (d3.y - d3.x), R * (-(d3.x + d3.y))); // * W8^3
  {
    float2 b0 = cadd(t0, t2), b1 = csub(t0, t2);
    float2 b2 = cadd(t1, t3), b3 = csub(t1, t3);
    a[0] = cadd(b0, b2);
    a[2] = cadd(b1, cmulnegi(b3));
    a[4] = csub(b0, b2);
    a[6] = cadd(b1, cmulposi(b3));
  }
  {
    float2 b0 = cadd(u0, u2), b1 = csub(u0, u2);
    float2 b2 = cadd(u1, u3), b3 = csub(u1, u3);
    a[1] = cadd(b0, b2);
    a[3] = cadd(b1, cmulnegi(b3));
    a[5] = csub(b0, b2);
    a[7] = cadd(b1, cmulposi(b3));
  }
}

// One radix-8 DIF pass; twiddle W_M^{j*r}, angle j*r/M rev (exact fp32,
// in [0,1)) -> v_sin/v_cos. M=8: last pass, no twiddle.
template <int STRIDE, int M>
__device__ __forceinline__ void fft_pass8(float2* Zl, int base, int j) {
  float2 v[8];
  #pragma unroll
  for (int p = 0; p < 8; p++) v[p] = Zl[SWZ(base + j + STRIDE * p)];
  dft8(v);
  #pragma unroll
  for (int r = 1; r < 8; r++) {
    if (M > 8) {
      int a = j * r;                                // < M
      float x = (float)a * (1.0f / (float)M);       // revolutions, exact
      float s = -__builtin_amdgcn_sinf(x);          // e^{-2 pi i x}
      float c =  __builtin_amdgcn_cosf(x);
      v[r] = cmulf(v[r], c, s);
    }
  }
  #pragma unroll
  for (int r = 0; r < 8; r++) Zl[SWZ(base + j + STRIDE * r)] = v[r];
}

// Chebyshev synthesis of ONE channel's 8 samples l = tid + 512k from the 16
// bins at CF[cbase..]. g(l+512) = T g(l) - g(l-512), T = 2 cos(2 pi f/8).
// Seeds x0 = f*tid/4096 rev exact (f*tid <= 2048*511 < 2^23).
__device__ __forceinline__ void synth8(const float4* CF, const float* CFf,
                                       int cbase, float tf, float* acc) {
  #pragma unroll
  for (int k = 0; k < 8; k++) acc[k] = 0.f;
  #pragma unroll 1
  for (int g = 0; g < 4; g++) {
    float u[4], v[4], T[4];
    #pragma unroll
    for (int j = 0; j < 4; j++) {
      float4 cf = CF[cbase + g * 4 + j];
      float f  = CFf[cbase + g * 4 + j];
      float x0 = f * tf * 2.44140625e-4f;
      x0 -= floorf(x0);
      float c0 = __builtin_amdgcn_cosf(x0);
      float s0 = __builtin_amdgcn_sinf(x0);
      float G = fmaf(cf.x, c0, cf.y * s0);    // g(tid)
      float H = fmaf(cf.y, c0, -cf.x * s0);   // b cos - a sin
      u[j] = G;
      v[j] = fmaf(G, cf.z, -H * cf.w);        // g(tid - 512)
      T[j] = cf.z + cf.z;
    }
    #pragma unroll
    for (int k = 0; k < 8; k += 2) {
      #pragma unroll
      for (int j = 0; j < 4; j++) { acc[k] += u[j];     v[j] = fmaf(T[j], u[j], -v[j]); }
      #pragma unroll
      for (int j = 0; j < 4; j++) { acc[k + 1] += v[j]; u[j] = fmaf(T[j], v[j], -u[j]); }
    }
  }
}

// ---------------- fused FFT + top-k + synthesis kernel ---------------------

__global__ __launch_bounds__(512, 3) void fourier_fused(
    const float4* __restrict__ X4, float4* __restrict__ O4) {
  __shared__ float2 Z[4096];        // one 4096-pt complex workspace (32 KB)
  __shared__ float4 CF[64];         // [gc*16+r] = (alpha, beta, cos_st, sin_st)
  __shared__ float  CFf[64];        // bin frequency f
  __shared__ float2 CAND[128];      // 8 waves x 16 local-top candidates

  const int tid = threadIdx.x;
  const int wv = tid >> 6;          // wave 0..7
  const int lane = tid & 63;
  // XCD-contiguous remap (bijective: 2048 blocks, 8 XCDs, 256 each):
  // 8 whole batches per XCD -> the 32 sibling blocks of a batch run on one
  // XCD and merge their strided float4 reads/writes in that XCD's L2.
  const int o = ((blockIdx.x & 7) << 8) + (blockIdx.x >> 3);
  const int b = o >> 5;
  const int q = o & 31;             // 4-channel group: channels 4q..4q+3

  const float inv = 2.44140625e-4f; // 1/4096
  const float4* src = X4 + (size_t)b * 4096 * 32 + q;

  // ---- two sequential {load, FFT, top-k} halves over the same Z ----
  #pragma unroll 1
  for (int half = 0; half < 2; half++) {
    // load channel pair of this half (half 1 re-reads the same float4;
    // L3-resident, no registers parked across phases). Chunked 2x4 to
    // halve the in-flight landing-zone registers (demand peak).
    #pragma unroll 1
    for (int kk = 0; kk < 2; kk++) {
      #pragma unroll
      for (int k = 0; k < 4; k++) {
        int l = tid + 512 * (4 * kk + k);
        float4 v = src[(size_t)l * 32];
        Z[SWZ(l)] = half ? make_float2(v.z, v.w) : make_float2(v.x, v.y);
      }
    }
    __syncthreads();

    // forward FFT: 4 radix-8 DIF passes; slot p ends holding bin drev8(p)
    fft_pass8<512, 4096>(Z, 0, tid);
    __syncthreads();
    fft_pass8<64, 512>(Z, (tid >> 6) << 9, tid & 63);
    __syncthreads();
    fft_pass8<8, 64>(Z, (tid >> 3) << 6, tid & 7);
    __syncthreads();
    fft_pass8<1, 8>(Z, tid << 3, 0);
    __syncthreads();

    // ---- scan: waves 0-3 -> even channel, waves 4-7 -> odd channel.
    // Wave wq of a channel covers f = lane + 64*(8*wq + k), k<8 (0..2047).
    const int ch = wv >> 2;
    const int wq = wv & 3;
    float m2[8];
    #pragma unroll
    for (int k = 0; k < 8; k++) {
      int f = lane + ((wq * 8 + k) << 6);
      float2 P = Z[SWZ(drev8(f))];
      float2 Q = Z[SWZ(drev8((4096 - f) & 4095))];
      float xr = ch ? (P.y + Q.y) : (P.x + Q.x);
      float xi = ch ? (Q.x - P.x) : (P.y - Q.y);
      m2[k] = xr * xr + xi * xi;   // 4*|X|^2 (ordering only)
    }
    float m2x = -1.f;              // Nyquist f=2048: wq==0, lane 0 only
    if (wq == 0 && lane == 0) {
      float2 P = Z[SWZ(4)];        // drev8(2048) == 4
      float t = ch ? P.y : P.x;
      m2x = 4.f * t * t;
    }

    // ---- wave-local top-16 (no barriers); lane r keeps round-r winner ----
    float cbv = -1.f; int cbf = 0;
    for (int r = 0; r < 16; r++) {
      float bv = -1e30f; int bf = 0;
      #pragma unroll
      for (int k = 0; k < 8; k++) {
        int f = lane + ((wq * 8 + k) << 6);
        if (m2[k] > bv) { bv = m2[k]; bf = f; }   // ascending: ties -> lower f
      }
      if (m2x > bv) { bv = m2x; bf = 2048; }
      #pragma unroll
      for (int off = 32; off; off >>= 1) {
        float ov = __shfl_down(bv, off);
        int   of = __shfl_down(bf, off);
        if (ov > bv || (ov == bv && of < bf)) { bv = ov; bf = of; }
      }
      bv = __shfl(bv, 0);
      bf = __shfl(bf, 0);
      if (lane == r) { cbv = bv; cbf = bf; }
      if (bf == 2048) {                          // knockout
        if (wq == 0 && lane == 0) m2x = -2.f;
      } else if ((bf & 63) == lane) {
        int kk = (bf >> 6) - 8 * wq;             // in [0,8) for owner wave
        #pragma unroll
        for (int k = 0; k < 8; k++) if (k == kk) m2[k] = -2.f;
      }
    }
    if (lane < 16) CAND[wv * 16 + lane] = make_float2(cbv, __int_as_float(cbf));
    __syncthreads();

    // ---- merge (waves 0 and 4): 64 candidates -> global top-16 + capture.
    // Total order (m2, -f) makes the hierarchical result exactly global.
    if (wq == 0) {
      float mv = CAND[(ch << 6) + lane].x;
      int   mf = __float_as_int(CAND[(ch << 6) + lane].y);
      for (int r = 0; r < 16; r++) {
        float bv = mv; int bf = mf;
        #pragma unroll
        for (int off = 32; off; off >>= 1) {
          float ov = __shfl_down(bv, off);
          int   of = __shfl_down(bf, off);
          if (ov > bv || (ov == bv && of < bf)) { bv = ov; bf = of; }
        }
        bf = __shfl(bf, 0);
        if (lane == r) {                         // capture coefficients
          float fv = (float)bf;
          float2 P = Z[SWZ(drev8(bf))];
          float2 Q = Z[SWZ(drev8((4096 - bf) & 4095))];
          float rA = ch ? 0.5f * (P.y + Q.y) : 0.5f * (P.x + Q.x);
          float rB = ch ? 0.5f * (Q.x - P.x) : 0.5f * (P.y - Q.y);
          float w = (bf == 0 || bf == 2048) ? inv : 2.f * inv;
          float dx = fv * 0.125f;                // f*512/4096 = f/8 rev
          dx -= floorf(dx);
          float cd = __builtin_amdgcn_cosf(dx);
          float sd = __builtin_amdgcn_sinf(dx);
          int gc = half * 2 + ch;                // block channel 0..3
          CF[gc * 16 + r] = make_float4(w * rA, -w * rB, cd, sd);
          CFf[gc * 16 + r] = fv;
        }
        if (mf == bf) mv = -2.f;                 // knockout (f unique in pool)
      }
    }
    __syncthreads();   // Z consumed; CF[2*half .. ] published
  }

  // ---- synthesis: 8 samples/thread/channel; ch0/ch1 staged through the
  // dead spectrum LDS (same-thread addresses, no barrier), ch2/ch3 in regs.
  float* Zf = (float*)Z;              // 8192 floats
  float acc[8], acc2[8], acc3[8];
  const float tf = (float)tid;
  synth8(CF, CFf, 0, tf, acc);
  #pragma unroll
  for (int k = 0; k < 8; k++) Zf[tid + 512 * k] = acc[k];
  synth8(CF, CFf, 16, tf, acc);
  #pragma unroll
  for (int k = 0; k < 8; k++) Zf[4096 + tid + 512 * k] = acc[k];
  synth8(CF, CFf, 32, tf, acc2);
  synth8(CF, CFf, 48, tf, acc3);

  // ---- store: float4 = 4 channels at one sample, sibling-merged lines ----
  float4* dst = O4 + (size_t)b * 4096 * 32 + q;
  #pragma unroll
  for (int k = 0; k < 8; k++) {
    int l = tid + 512 * k;
    dst[(size_t)l * 32] = make_float4(Zf[l], Zf[4096 + l], acc2[k], acc3[k]);
  }
}

extern "C" void kernel_launch(void* const* d_in, const int* in_sizes, int n_in,
                              void* d_out, int out_size, void* d_ws, size_t ws_size,
                              hipStream_t stream) {
  (void)in_sizes; (void)n_in; (void)ws_size; (void)out_size; (void)d_ws;
  const float4* x = (const float4*)d_in[0];
  float4* out = (float4*)d_out;

  fourier_fused<<<dim3(64 * 32), dim3(512), 0, stream>>>(x, out);
}

// Round 14
// 831.394 us; speedup vs baseline: 1.0136x; 1.0136x over previous
//
#include <hip/hip_runtime.h>

// FourierBlock: per (b, c): rfft(4096) -> keep top-16 |X| bins -> irfft.
//
// Round 17: return to the session-best round-5 kernel (352 us: 256 thr,
// radix-16 FFT over 33 KB, occ 42%, VGPR 64 natural, zero spill) and fix
// its only weakness -- float2 strided I/O (542 MB total HBM traffic; ideal
// is 260). Key asymmetry: at 256 thr/block, 4 blocks/CU (LDS-bound) needs
// only 4 waves/SIMD -> VGPR cap 128 -> round 5 had 64 regs of FREE
// headroom. Spend it: 4 channels/block, float4 load once (ch2/3 parked in
// 32 regs), two sequential {FFT, top-k} halves over one 32 KB Z, float4
// merged store (r4/r11 proven signature: WRITE == 131072 KB). Peak live
// ~95-100 < 128: slack squeeze only, unlike the 512-thr family whose
// demand (~100+) could never fit the 64-reg level that 8 waves/SIMD needs
// (cap64 -> heavy spill r12; cap85 -> mild spill r13; cap128 -> occ 23%).

#define SWZ(i) ((i) ^ (((i) >> 4) & 15))

__device__ __forceinline__ int drev16(int x) {
  // reverse the three base-16 digits of a 12-bit index (involution)
  return ((x & 15) << 8) | (x & 0xF0) | ((x >> 8) & 15);
}

__device__ __forceinline__ float2 cmulf(float2 a, float c, float s) {
  return make_float2(a.x * c - a.y * s, a.x * s + a.y * c);
}

__device__ __forceinline__ void bfly4(float2& a0, float2& a1, float2& a2, float2& a3) {
  float ar = a0.x + a2.x, ai = a0.y + a2.y;
  float br = a0.x - a2.x, bi = a0.y - a2.y;
  float cr = a1.x + a3.x, ci = a1.y + a3.y;
  float dr = a1.x - a3.x, di = a1.y - a3.y;
  a0 = make_float2(ar + cr, ai + ci);
  a1 = make_float2(br + di, bi - dr);   // b - i*d
  a2 = make_float2(ar - cr, ai - ci);
  a3 = make_float2(br - di, bi + dr);   // b + i*d
}

// 16-point DIF DFT in registers; output slot s holds bin rev4(s).
__device__ __forceinline__ void dft16(float2* v) {
  const float C16[10] = {1.f, 0.9238795325112867f, 0.7071067811865476f, 0.3826834323650898f, 0.f,
                         -0.3826834323650898f, -0.7071067811865476f, -0.9238795325112867f, -1.f,
                         -0.9238795325112867f};
  const float S16[10] = {0.f, -0.3826834323650898f, -0.7071067811865476f, -0.9238795325112867f, -1.f,
                         -0.9238795325112867f, -0.7071067811865476f, -0.3826834323650898f, 0.f,
                         0.3826834323650898f};
  #pragma unroll
  for (int j2 = 0; j2 < 4; j2++) {
    bfly4(v[j2], v[j2 + 4], v[j2 + 8], v[j2 + 12]);
    if (j2 > 0) {
      v[j2 + 4]  = cmulf(v[j2 + 4],  C16[j2],     S16[j2]);
      v[j2 + 8]  = cmulf(v[j2 + 8],  C16[2 * j2], S16[2 * j2]);
      v[j2 + 12] = cmulf(v[j2 + 12], C16[3 * j2], S16[3 * j2]);
    }
  }
  #pragma unroll
  for (int r2 = 0; r2 < 4; r2++) bfly4(v[4 * r2], v[4 * r2 + 1], v[4 * r2 + 2], v[4 * r2 + 3]);
}

// One radix-16 DIF pass; M = twiddle span (0 = last pass, none).
// Twiddle angle a/M revolutions: exact fp32, in [0,1) -> v_sin/v_cos.
template <int STRIDE, int M>
__device__ __forceinline__ void fft_pass(float2* Zl, int base, int j) {
  const int kRev4[16] = {0, 4, 8, 12, 1, 5, 9, 13, 2, 6, 10, 14, 3, 7, 11, 15};
  float2 v[16];
  #pragma unroll
  for (int p = 0; p < 16; p++) v[p] = Zl[SWZ(base + j + STRIDE * p)];
  dft16(v);
  #pragma unroll
  for (int r = 0; r < 16; r++) {
    float2 u = v[kRev4[r]];
    if (M > 0 && r > 0) {
      int a = (j * r) & (M - 1);
      float x = (float)a * (1.0f / (float)M);       // revolutions, exact
      float s = -__builtin_amdgcn_sinf(x);          // e^{-2 pi i x}
      float c =  __builtin_amdgcn_cosf(x);
      u = cmulf(u, c, s);
    }
    Zl[SWZ(base + j + STRIDE * r)] = u;
  }
}

// Chebyshev synthesis of one channel's 16 samples l = tid + 256k from the
// 16 bins at CF[cbase..]. g(l+256) = T g(l) - g(l-256), T = 2 cos(2pi f/16).
// Seeds x0 = f*tid/4096 rev exact (f*tid <= 2048*255 < 2^19).
__device__ __forceinline__ void synthc(const float4* CF, const float* CFf,
                                       int cbase, float tf, float* acc) {
  #pragma unroll
  for (int k = 0; k < 16; k++) acc[k] = 0.f;
  #pragma unroll 1
  for (int g = 0; g < 4; g++) {
    float u[4], v[4], T[4];
    #pragma unroll
    for (int j = 0; j < 4; j++) {
      float4 cf = CF[cbase + g * 4 + j];
      float f  = CFf[cbase + g * 4 + j];
      float x0 = f * tf * 2.44140625e-4f;
      x0 -= floorf(x0);
      float c0 = __builtin_amdgcn_cosf(x0);
      float s0 = __builtin_amdgcn_sinf(x0);
      float G = fmaf(cf.x, c0, cf.y * s0);    // g(tid)
      float H = fmaf(cf.y, c0, -cf.x * s0);   // b cos - a sin
      u[j] = G;
      v[j] = fmaf(G, cf.z, -H * cf.w);        // g(tid - 256)
      T[j] = cf.z + cf.z;
    }
    #pragma unroll
    for (int k = 0; k < 16; k += 2) {
      #pragma unroll
      for (int j = 0; j < 4; j++) { acc[k] += u[j];     v[j] = fmaf(T[j], u[j], -v[j]); }
      #pragma unroll
      for (int j = 0; j < 4; j++) { acc[k + 1] += v[j]; u[j] = fmaf(T[j], v[j], -u[j]); }
    }
  }
}

// ---------------- fused FFT + top-k + synthesis kernel ---------------------

__global__ __launch_bounds__(256, 4) void fourier_fused(
    const float4* __restrict__ X4, float4* __restrict__ O4) {
  __shared__ float2 Z[4096];        // one 4096-pt complex workspace (32 KB)
  __shared__ float4 CF[64];         // [gc*16+r] = (alpha, beta, cos_st, sin_st)
  __shared__ float  CFf[64];        // bin frequency f

  const int tid = threadIdx.x;
  const int wv = tid >> 6;          // wave 0..3
  const int lane = tid & 63;
  // XCD-contiguous remap (bijective: 2048 blocks, 8 XCDs, 256 each):
  // 8 whole batches per XCD -> the 32 sibling blocks of a batch run on one
  // XCD and merge their strided float4 reads/writes in that XCD's L2.
  const int o = ((blockIdx.x & 7) << 8) + (blockIdx.x >> 3);
  const int b = o >> 5;
  const int q = o & 31;             // 4-channel group: channels 4q..4q+3

  const float inv = 2.44140625e-4f; // 1/4096
  const float4* src = X4 + (size_t)b * 4096 * 32 + q;

  // ---- load once: x[b, l, 4q..4q+3] = one float4. (ch0,ch1) -> Z as
  // complex; (ch2,ch3) park in 32 registers until half 1 (free: VGPR cap
  // is 128 at 4 waves/SIMD and round-5's base kernel used only 64).
  float pr[16], pi[16];
  #pragma unroll
  for (int k = 0; k < 16; k++) {
    int l = tid + 256 * k;
    float4 v = src[(size_t)l * 32];
    Z[SWZ(l)] = make_float2(v.x, v.y);
    pr[k] = v.z;
    pi[k] = v.w;
  }
  __syncthreads();

  // ---- two sequential {FFT, top-k} halves over the same Z ----
  #pragma unroll 1
  for (int half = 0; half < 2; half++) {
    if (half) {                     // Z dead after top-k #0: unpark ch2/3
      #pragma unroll
      for (int k = 0; k < 16; k++) Z[SWZ(tid + 256 * k)] = make_float2(pr[k], pi[k]);
      __syncthreads();
    }

    // forward FFT (3 radix-16 passes), output hex-digit-reversed
    fft_pass<256, 4096>(Z, 0, tid);
    __syncthreads();
    fft_pass<16, 256>(Z, (tid >> 4) << 8, tid & 15);
    __syncthreads();
    fft_pass<1, 0>(Z, tid << 4, 0);
    __syncthreads();

    // top-16: wave 0 = even channel of this half, wave 1 = odd channel
    if (wv < 2) {
      const int ch = wv;
      float m2[32];
      #pragma unroll
      for (int k = 0; k < 32; k++) {
        int f = lane + (k << 6);
        float2 P = Z[SWZ(drev16(f))];
        float2 Q = Z[SWZ(drev16((4096 - f) & 4095))];
        float xr = ch ? (P.y + Q.y) : (P.x + Q.x);
        float xi = ch ? (Q.x - P.x) : (P.y - Q.y);
        m2[k] = xr * xr + xi * xi;   // 4*|X|^2 (ordering only)
      }
      float m2x = -1.f;              // bin f=2048 (Nyquist), lane 0 only
      if (lane == 0) {
        float2 P = Z[SWZ(8)];        // drev16(2048) == 8
        float t = ch ? P.y : P.x;
        m2x = 4.f * t * t;
      }
      for (int r = 0; r < 16; r++) {
        float bv = -1e30f; int bf = 0;
        #pragma unroll
        for (int k = 0; k < 32; k++) {
          int f = lane + (k << 6);
          if (m2[k] > bv) { bv = m2[k]; bf = f; }   // ties -> lower f
        }
        if (m2x > bv) { bv = m2x; bf = 2048; }
        #pragma unroll
        for (int off = 32; off; off >>= 1) {
          float ov = __shfl_down(bv, off);
          int   of = __shfl_down(bf, off);
          if (ov > bv || (ov == bv && of < bf)) { bv = ov; bf = of; }
        }
        bf = __shfl(bf, 0);          // broadcast winner bin
        if (lane == r) {             // capture coefficients in lane r
          float fv = (float)bf;
          float2 P = Z[SWZ(drev16(bf))];
          float2 Q = Z[SWZ(drev16((4096 - bf) & 4095))];
          float rA = ch ? 0.5f * (P.y + Q.y) : 0.5f * (P.x + Q.x);
          float rB = ch ? 0.5f * (Q.x - P.x) : 0.5f * (P.y - Q.y);
          float w = (bf == 0 || bf == 2048) ? inv : 2.f * inv;
          float dx = fv * 0.0625f;   // f*256/4096 = f/16 rev (exact)
          dx -= floorf(dx);
          float cd = __builtin_amdgcn_cosf(dx);
          float sd = __builtin_amdgcn_sinf(dx);
          int gc = half * 2 + ch;    // block channel 0..3
          CF[gc * 16 + r] = make_float4(w * rA, -w * rB, cd, sd);
          CFf[gc * 16 + r] = fv;
        }
        if (bf == 2048) {            // knockout
          if (lane == 0) m2x = -2.f;
        } else if ((bf & 63) == lane) {
          int kk = bf >> 6;
          #pragma unroll
          for (int k = 0; k < 32; k++) if (k == kk) m2[k] = -2.f;
        }
      }
    }
    __syncthreads();   // Z consumed; CF of this half published
  }

  // ---- synthesis: 16 samples/thread/channel; ch0/ch1 staged through the
  // dead spectrum LDS (8192 floats exactly; same-thread addresses, no
  // barrier needed), ch2/ch3 in registers.
  float* Zf = (float*)Z;
  float acc[16], acc2[16], acc3[16];
  const float tf = (float)tid;
  synthc(CF, CFf, 0, tf, acc);
  #pragma unroll
  for (int k = 0; k < 16; k++) Zf[tid + 256 * k] = acc[k];
  synthc(CF, CFf, 16, tf, acc);
  #pragma unroll
  for (int k = 0; k < 16; k++) Zf[4096 + tid + 256 * k] = acc[k];
  synthc(CF, CFf, 32, tf, acc2);
  synthc(CF, CFf, 48, tf, acc3);

  // ---- store: float4 = 4 channels at one sample, sibling-merged lines ----
  float4* dst = O4 + (size_t)b * 4096 * 32 + q;
  #pragma unroll
  for (int k = 0; k < 16; k++) {
    int l = tid + 256 * k;
    dst[(size_t)l * 32] = make_float4(Zf[l], Zf[4096 + l], acc2[k], acc3[k]);
  }
}

extern "C" void kernel_launch(void* const* d_in, const int* in_sizes, int n_in,
                              void* d_out, int out_size, void* d_ws, size_t ws_size,
                              hipStream_t stream) {
  (void)in_sizes; (void)n_in; (void)ws_size; (void)out_size; (void)d_ws;
  const float4* x = (const float4*)d_in[0];
  float4* out = (float4*)d_out;

  fourier_fused<<<dim3(64 * 32), dim3(256), 0, stream>>>(x, out);
}